// Round 4
// baseline (279.563 us; speedup 1.0000x reference)
//
#include <hip/hip_runtime.h>

// LengthRegulator: expand x (B,T,H) by per-token durations into (B,MAXLEN,H),
// plus sinusoidal positional rows per within-token offset, plus mel lengths.
// B=64, T=160, H=256, MAXLEN=2000 (fixed by the harness's setup_inputs).
//
// v2b: two-kernel split. Kernel A (one block per batch) does the duration scan
// ONCE and materializes a frame->(token,pos_within) map in the workspace.
// Kernel B is a pure streaming gather/copy: no scan, no binary search, no LDS,
// no barriers -> should sit on the write roofline (~262 MB of stores).
constexpr int B      = 64;
constexpr int T      = 160;
constexpr int H      = 256;
constexpr int MAXLEN = 2000;
constexpr int FPB    = 16;   // frames per block in expand kernel (4 waves x 4 frames)
constexpr int NTH    = 256;

typedef float floatx4 __attribute__((ext_vector_type(4)));

// ---------------- Kernel A: per-batch scan + map build (64 blocks) ----------
// map[b*MAXLEN + f] = (token << 8) | pos_within   for valid frames (pw in 0..11)
//                   = -1                          for the invalid tail
__global__ __launch_bounds__(NTH) void build_map_kernel(
    const int* __restrict__ duration,
    int*       __restrict__ map,
    float*     __restrict__ out)      // only for the mel_len chunk
{
    __shared__ int s_scan[NTH];
    const int b   = blockIdx.x;
    const int tid = threadIdx.x;

    int d = (tid < T) ? duration[b * T + tid] : 0;
    s_scan[tid] = d;
    __syncthreads();
    #pragma unroll
    for (int off = 1; off < NTH; off <<= 1) {
        int v   = s_scan[tid];
        int add = (tid >= off) ? s_scan[tid - off] : 0;
        __syncthreads();
        s_scan[tid] = v + add;
        __syncthreads();
    }
    const int csum    = s_scan[tid];        // inclusive prefix (valid for tid < T)
    const int excl    = csum - d;           // exclusive prefix
    const int mel_len = s_scan[T - 1];

    // mel_len output (as float32, third chunk of the flat output buffer)
    if (tid == 0)
        out[(size_t)2 * B * MAXLEN * H + b] = (float)mel_len;

    int* bm = map + b * MAXLEN;

    // invalid tail
    for (int f = mel_len + tid; f < MAXLEN; f += NTH)
        bm[f] = -1;

    // scatter: token tid owns frames [excl, csum). duration < 12 so pw fits 8 bits.
    if (tid < T) {
        for (int f = excl; f < csum; ++f)
            bm[f] = (tid << 8) | (f - excl);
    }
}

// ---------------- Kernel B: streaming expand (125 x 64 blocks) --------------
__global__ __launch_bounds__(NTH) void expand_kernel(
    const float* __restrict__ x,
    const float* __restrict__ pos_enc,
    const int*   __restrict__ map,
    float*       __restrict__ out)
{
    const int tid  = threadIdx.x;
    const int b    = blockIdx.y;
    const int wave = tid >> 6;   // 0..3
    const int lane = tid & 63;   // float4 index within the 256-wide row

    const size_t out_base = (size_t)b * MAXLEN * H;
    const size_t pos_base = (size_t)B * MAXLEN * H + out_base;
    const int f0 = blockIdx.x * FPB;          // MAXLEN % FPB == 0, no tail check
    const int* bm = map + b * MAXLEN;

    #pragma unroll
    for (int i = 0; i < FPB / 4; ++i) {
        const int f = f0 + wave + 4 * i;
        const int m = bm[f];                  // wave-uniform broadcast load

        floatx4 xo = (floatx4)0.f;
        floatx4 po = (floatx4)0.f;
        if (m >= 0) {
            const int t  = m >> 8;
            const int pw = m & 255;
            xo = ((const floatx4*)(x       + ((size_t)b * T + t) * H))[lane];
            po = ((const floatx4*)(pos_enc + (size_t)pw      * H))[lane];
        }
        // Output is write-once, never re-read: keep it out of L2 so x/pos_enc/map
        // stay resident for the gathers.
        __builtin_nontemporal_store(xo, (floatx4*)(out + out_base + (size_t)f * H) + lane);
        __builtin_nontemporal_store(po, (floatx4*)(out + pos_base + (size_t)f * H) + lane);
    }
}

// ---------------- Fallback: original fused kernel (if ws too small) ---------
__global__ __launch_bounds__(NTH) void lr_kernel(
    const float* __restrict__ x,
    const float* __restrict__ pos_enc,
    const int*   __restrict__ duration,
    float*       __restrict__ out)
{
    __shared__ int s_scan[NTH];
    __shared__ int s_csum[T];
    __shared__ int s_excl[T];

    const int b   = blockIdx.y;
    const int tid = threadIdx.x;

    int d = (tid < T) ? duration[b * T + tid] : 0;
    s_scan[tid] = d;
    __syncthreads();
    #pragma unroll
    for (int off = 1; off < NTH; off <<= 1) {
        int v   = s_scan[tid];
        int add = (tid >= off) ? s_scan[tid - off] : 0;
        __syncthreads();
        s_scan[tid] = v + add;
        __syncthreads();
    }
    if (tid < T) {
        s_csum[tid] = s_scan[tid];
        s_excl[tid] = s_scan[tid] - d;
    }
    __syncthreads();

    const int mel_len = s_csum[T - 1];
    if (blockIdx.x == 0 && tid == 0) {
        out[(size_t)2 * B * MAXLEN * H + b] = (float)mel_len;
    }

    const int wave = tid >> 6;
    const int lane = tid & 63;
    const size_t out_base = (size_t)b * MAXLEN * H;
    const size_t pos_base = (size_t)B * MAXLEN * H + out_base;
    const int f0 = blockIdx.x * FPB;

    for (int i = wave; i < FPB; i += 4) {
        const int f = f0 + i;
        if (f >= MAXLEN) break;
        const bool valid = (f < mel_len);

        int lo = 0, hi = T;
        while (lo < hi) {
            int mid = (lo + hi) >> 1;
            if (s_csum[mid] <= f) lo = mid + 1; else hi = mid;
        }
        const int idx = min(lo, T - 1);

        float4 xo = make_float4(0.f, 0.f, 0.f, 0.f);
        float4 po = xo;
        if (valid) {
            const int pw = f - s_excl[idx];
            xo = ((const float4*)(x + ((size_t)b * T + idx) * H))[lane];
            po = ((const float4*)(pos_enc + (size_t)pw * H))[lane];
        }
        ((float4*)(out + out_base + (size_t)f * H))[lane] = xo;
        ((float4*)(out + pos_base + (size_t)f * H))[lane] = po;
    }
}

extern "C" void kernel_launch(void* const* d_in, const int* in_sizes, int n_in,
                              void* d_out, int out_size, void* d_ws, size_t ws_size,
                              hipStream_t stream)
{
    const float* x        = (const float*)d_in[0];
    const float* pos_enc  = (const float*)d_in[1];
    const int*   duration = (const int*)d_in[2];
    float*       out      = (float*)d_out;

    const size_t map_bytes = (size_t)B * MAXLEN * sizeof(int);
    if (d_ws != nullptr && ws_size >= map_bytes) {
        int* map = (int*)d_ws;
        build_map_kernel<<<dim3(B), NTH, 0, stream>>>(duration, map, out);
        expand_kernel<<<dim3(MAXLEN / FPB, B), NTH, 0, stream>>>(x, pos_enc, map, out);
    } else {
        dim3 grid((MAXLEN + FPB - 1) / FPB, B);
        lr_kernel<<<grid, NTH, 0, stream>>>(x, pos_enc, duration, out);
    }
}

// Round 5
// 271.035 us; speedup vs baseline: 1.0315x; 1.0315x over previous
//
#include <hip/hip_runtime.h>

// LengthRegulator: expand x (B,T,H) by per-token durations into (B,MAXLEN,H),
// plus sinusoidal positional rows per within-token offset, plus mel lengths.
// B=64, T=160, H=256, MAXLEN=2000 (fixed by the harness's setup_inputs).
//
// v3: two-kernel split (scan once in kernel A), branchless streaming expand
// in kernel B with plain (cached) float4 stores.
//   - v2b's nontemporal stores REGRESSED (+~10 us): reverted. nt vector stores
//     may scalarize, and bypassing L2 forfeits dirty-line write buffering.
//   - expand body is now branchless: all map loads hoisted, all row loads
//     unconditional (invalid frames read token 0 - a broadcast L2 hit),
//     result scaled by valid?1:0. Max loads in flight, no exec-mask churn.
constexpr int B      = 64;
constexpr int T      = 160;
constexpr int H      = 256;
constexpr int MAXLEN = 2000;
constexpr int FPB    = 16;   // frames per block in expand kernel (4 waves x 4 frames)
constexpr int NTH    = 256;

// ---------------- Kernel A: per-batch scan + map build (64 blocks) ----------
// map[b*MAXLEN + f] = (token << 8) | pos_within   for valid frames (pw in 0..11)
//                   = -1                          for the invalid tail
__global__ __launch_bounds__(NTH) void build_map_kernel(
    const int* __restrict__ duration,
    int*       __restrict__ map,
    float*     __restrict__ out)      // only for the mel_len chunk
{
    __shared__ int s_scan[NTH];
    const int b   = blockIdx.x;
    const int tid = threadIdx.x;

    int d = (tid < T) ? duration[b * T + tid] : 0;
    s_scan[tid] = d;
    __syncthreads();
    #pragma unroll
    for (int off = 1; off < NTH; off <<= 1) {
        int v   = s_scan[tid];
        int add = (tid >= off) ? s_scan[tid - off] : 0;
        __syncthreads();
        s_scan[tid] = v + add;
        __syncthreads();
    }
    const int csum    = s_scan[tid];        // inclusive prefix (valid for tid < T)
    const int excl    = csum - d;           // exclusive prefix
    const int mel_len = s_scan[T - 1];

    // mel_len output (as float32, third chunk of the flat output buffer)
    if (tid == 0)
        out[(size_t)2 * B * MAXLEN * H + b] = (float)mel_len;

    int* bm = map + b * MAXLEN;

    // invalid tail
    for (int f = mel_len + tid; f < MAXLEN; f += NTH)
        bm[f] = -1;

    // scatter: token tid owns frames [excl, csum). duration < 12 so pw fits 8 bits.
    if (tid < T) {
        for (int f = excl; f < csum; ++f)
            bm[f] = (tid << 8) | (f - excl);
    }
}

// ---------------- Kernel B: branchless streaming expand (125 x 64 blocks) ---
__global__ __launch_bounds__(NTH) void expand_kernel(
    const float* __restrict__ x,
    const float* __restrict__ pos_enc,
    const int*   __restrict__ map,
    float*       __restrict__ out)
{
    const int tid  = threadIdx.x;
    const int b    = blockIdx.y;
    const int wave = tid >> 6;   // 0..3
    const int lane = tid & 63;   // float4 index within the 256-wide row

    const size_t out_base = (size_t)b * MAXLEN * H;
    const size_t pos_base = (size_t)B * MAXLEN * H + out_base;
    const int f0 = blockIdx.x * FPB;          // MAXLEN % FPB == 0, no tail check
    const int* bm = map + b * MAXLEN;

    // 1) all map loads in flight (wave-uniform broadcast loads)
    int m[4];
    #pragma unroll
    for (int i = 0; i < 4; ++i)
        m[i] = bm[f0 + wave + 4 * i];

    // 2) all row loads in flight, unconditional (invalid -> token 0 / pw 0,
    //    a broadcast L2 hit; result zeroed below)
    float4 xo[4], po[4];
    #pragma unroll
    for (int i = 0; i < 4; ++i) {
        const int mm = (m[i] < 0) ? 0 : m[i];
        const int t  = mm >> 8;
        const int pw = mm & 255;
        xo[i] = ((const float4*)(x       + ((size_t)b * T + t) * H))[lane];
        po[i] = ((const float4*)(pos_enc + (size_t)pw      * H))[lane];
    }

    // 3) scale by validity, store (plain cached stores)
    #pragma unroll
    for (int i = 0; i < 4; ++i) {
        const float s = (m[i] >= 0) ? 1.0f : 0.0f;
        const int   f = f0 + wave + 4 * i;
        float4 a = make_float4(xo[i].x * s, xo[i].y * s, xo[i].z * s, xo[i].w * s);
        float4 p = make_float4(po[i].x * s, po[i].y * s, po[i].z * s, po[i].w * s);
        ((float4*)(out + out_base + (size_t)f * H))[lane] = a;
        ((float4*)(out + pos_base + (size_t)f * H))[lane] = p;
    }
}

// ---------------- Fallback: original fused kernel (if ws too small) ---------
__global__ __launch_bounds__(NTH) void lr_kernel(
    const float* __restrict__ x,
    const float* __restrict__ pos_enc,
    const int*   __restrict__ duration,
    float*       __restrict__ out)
{
    __shared__ int s_scan[NTH];
    __shared__ int s_csum[T];
    __shared__ int s_excl[T];

    const int b   = blockIdx.y;
    const int tid = threadIdx.x;

    int d = (tid < T) ? duration[b * T + tid] : 0;
    s_scan[tid] = d;
    __syncthreads();
    #pragma unroll
    for (int off = 1; off < NTH; off <<= 1) {
        int v   = s_scan[tid];
        int add = (tid >= off) ? s_scan[tid - off] : 0;
        __syncthreads();
        s_scan[tid] = v + add;
        __syncthreads();
    }
    if (tid < T) {
        s_csum[tid] = s_scan[tid];
        s_excl[tid] = s_scan[tid] - d;
    }
    __syncthreads();

    const int mel_len = s_csum[T - 1];
    if (blockIdx.x == 0 && tid == 0) {
        out[(size_t)2 * B * MAXLEN * H + b] = (float)mel_len;
    }

    const int wave = tid >> 6;
    const int lane = tid & 63;
    const size_t out_base = (size_t)b * MAXLEN * H;
    const size_t pos_base = (size_t)B * MAXLEN * H + out_base;
    const int f0 = blockIdx.x * FPB;

    for (int i = wave; i < FPB; i += 4) {
        const int f = f0 + i;
        if (f >= MAXLEN) break;
        const bool valid = (f < mel_len);

        int lo = 0, hi = T;
        while (lo < hi) {
            int mid = (lo + hi) >> 1;
            if (s_csum[mid] <= f) lo = mid + 1; else hi = mid;
        }
        const int idx = min(lo, T - 1);

        float4 xo = make_float4(0.f, 0.f, 0.f, 0.f);
        float4 po = xo;
        if (valid) {
            const int pw = f - s_excl[idx];
            xo = ((const float4*)(x + ((size_t)b * T + idx) * H))[lane];
            po = ((const float4*)(pos_enc + (size_t)pw * H))[lane];
        }
        ((float4*)(out + out_base + (size_t)f * H))[lane] = xo;
        ((float4*)(out + pos_base + (size_t)f * H))[lane] = po;
    }
}

extern "C" void kernel_launch(void* const* d_in, const int* in_sizes, int n_in,
                              void* d_out, int out_size, void* d_ws, size_t ws_size,
                              hipStream_t stream)
{
    const float* x        = (const float*)d_in[0];
    const float* pos_enc  = (const float*)d_in[1];
    const int*   duration = (const int*)d_in[2];
    float*       out      = (float*)d_out;

    const size_t map_bytes = (size_t)B * MAXLEN * sizeof(int);
    if (d_ws != nullptr && ws_size >= map_bytes) {
        int* map = (int*)d_ws;
        build_map_kernel<<<dim3(B), NTH, 0, stream>>>(duration, map, out);
        expand_kernel<<<dim3(MAXLEN / FPB, B), NTH, 0, stream>>>(x, pos_enc, map, out);
    } else {
        dim3 grid((MAXLEN + FPB - 1) / FPB, B);
        lr_kernel<<<grid, NTH, 0, stream>>>(x, pos_enc, duration, out);
    }
}